// Round 8
// baseline (171.580 us; speedup 1.0000x reference)
//
#include <hip/hip_runtime.h>

#define HID   384
#define K_PE  768     // 3*16*16
#define IMGST 150528  // 3*224*224 floats per image
#define POS   196

typedef unsigned short ushort_t;
using f32x4  = __attribute__((ext_vector_type(4))) float;
using short8 = __attribute__((ext_vector_type(8))) short;

// ---- bf16 helpers ----------------------------------------------------------
__device__ __forceinline__ unsigned bfpack(float lo, float hi) {   // RNE (prep)
    union { float f; unsigned u; } a, b; a.f = lo; b.f = hi;
    unsigned ra = (a.u + 0x7fffu + ((a.u >> 16) & 1u)) >> 16;
    unsigned rb = (b.u + 0x7fffu + ((b.u >> 16) & 1u)) & 0xffff0000u;
    return ra | rb;
}
__device__ __forceinline__ unsigned cvtpk(float lo, float hi) {    // RNE, 1 instr
    unsigned r;
    asm("v_cvt_pk_bf16_f32 %0, %1, %2" : "=v"(r) : "v"(lo), "v"(hi));
    return r;
}
__device__ __forceinline__ float bf2f(unsigned hibits) {
    union { unsigned u; float f; } v; v.u = hibits; return v.f;
}

// ---------------- prep: zero scalars + swizzle W into B-frag order ----------
// Wfrag: [nt(24)][kc(24)][lane(64)][8] bf16; B-frag n = nt*16 + (lane&15),
// k = kc*32 + (lane>>4)*8 + j. grid 144 x 256 = 384 rows x 96 k-octets.
__global__ __launch_bounds__(256) void prep(const float* __restrict__ W,
                                            ushort_t* __restrict__ Wfrag,
                                            float* __restrict__ scal) {
    const int t = blockIdx.x * 256 + threadIdx.x;
    if (t < 4) scal[t] = 0.f;                  // T, S, pad, done-counter
    const int n  = t / 96;                     // 0..383
    const int ko = t - n * 96;                 // k-octet
    const float4 a  = *(const float4*)(W + (size_t)n * K_PE + ko * 8);
    const float4 bb = *(const float4*)(W + (size_t)n * K_PE + ko * 8 + 4);
    uint4 pq;
    pq.x = bfpack(a.x, a.y);   pq.y = bfpack(a.z, a.w);
    pq.z = bfpack(bb.x, bb.y); pq.w = bfpack(bb.z, bb.w);
    const int nt    = n >> 4;
    const int kc    = ko >> 2;
    const int lanew = (ko & 3) * 16 + (n & 15);
    ((uint4*)Wfrag)[(nt * 24 + kc) * 64 + lanew] = pq;
}

// ---------------- fused im2col + GEMM + softmax ------------------------------
// R8: HALF-M blocks for wave-level stall overlap. grid 896 = 14 pi x 64 img.
// block 256 = 4 n-waves (96 cols each). M = 16 rows/tensor = 1 img x 14 pj
// (+2 pad dup of row 13). 3.5 blocks/CU (launch_bounds (256,4) caps VGPR at
// 128) -> ~3.5 waves/SIMD: while one wave sits at its per-iter vmcnt stall
// (~900 cyc, structural: B-frag waits drain the shared VMEM queue, proven
// by R5/R6/R7 all landing at 1.35 TB/s), the other waves' MFMA blocks fill
// the SIMD. K-loop: 12 steps of K=64 (c = kk>>2, kh-quad = kk&3); per step
// the block reads 8 contiguous 896-B HBM rows, packs bf16 into LDS.
// Epilogue: fused softmax; T (fp32) -> atomicAdd; (logp,q) packed bf16x2 ->
// Zg[p][img][c].
__global__ __launch_bounds__(256, 4) void pef(
    const float* __restrict__ x, const float* __restrict__ y,
    const ushort_t* __restrict__ Wfrag, const float* __restrict__ bias,
    float* __restrict__ scal, unsigned* __restrict__ Zg) {
    const int blk = blockIdx.x;        // 0..895
    const int pi  = blk >> 6;          // 0..13
    const int img = blk & 63;          // 0..63

    // As: [buf][oct(8) @228 ush][t(2)][pj(14)][8 ush]  (228 pad: bank rotate)
    __shared__ __align__(16) ushort_t As[2][8 * 228];
    __shared__ float Smx[4][16], Ssx[4][16], Smy[4][16], Ssy[4][16];
    __shared__ float sT[4];

    const int tid  = threadIdx.x;
    const int wave = tid >> 6;         // n-wave: cols wave*96..+96
    const int lane = tid & 63;
    const int lm   = lane & 15;
    const int lq   = lane >> 4;

    // ---- staging ids: rr = (t, kh_local); sj = (pj, q). 8 rows x 28 lanes.
    const int rr   = tid >> 5;         // 0..7
    const int sj   = tid & 31;         // active < 28
    const int st   = rr >> 2;          // tensor
    const int skh  = rr & 3;           // kh within quad
    const int sq   = sj & 1;
    const int spj  = sj >> 1;
    const bool sact = sj < 28;
    const float* srow = (st ? y : x) +
        (size_t)img * IMGST + pi * 3584 + skh * 224 + sj * 8;
    const int aoff = (skh * 2 + sq) * 228 + st * 112 + spj * 8;

    // ---- A-frag read offsets: m = lm (clamp 13) -> pj; octet = ks*4+lq
    int ard[2];      // [t]; add (ks*4+lq)*228 for the octet
    {
        int m = lm; if (m > 13) m = 13;    // pad rows dup row 13
        ard[0] = m * 8;
        ard[1] = 112 + m * 8;
    }

    f32x4 accx[6] = {};
    f32x4 accy[6] = {};

#define LOADB(B, KC)                                                          \
    {                                                                         \
        _Pragma("unroll")                                                     \
        for (int ni = 0; ni < 6; ++ni)                                        \
            B[ni] = *(const short8*)(Wfrag +                                  \
                    ((size_t)((wave * 6 + ni) * 24 + (KC)) * 64 + lane) * 8); \
    }
#define MFMA12(AFX, AFY, B)                                                   \
    {                                                                         \
        _Pragma("unroll")                                                     \
        for (int ni = 0; ni < 6; ++ni) {                                      \
            accx[ni] = __builtin_amdgcn_mfma_f32_16x16x32_bf16(               \
                AFX, B[ni], accx[ni], 0, 0, 0);                               \
            accy[ni] = __builtin_amdgcn_mfma_f32_16x16x32_bf16(               \
                AFY, B[ni], accy[ni], 0, 0, 0);                               \
        }                                                                     \
    }

    // ---- prologue: direct-stage step 0, preload B(kk=0, ks=0)
    short8 b0[6], b1[6], bn[6];
    LOADB(b0, 0)
    if (sact) {
        const float4 f0 = *(const float4*)(srow);
        const float4 f1 = *(const float4*)(srow + 4);
        uint4 p0;
        p0.x = bfpack(f0.x, f0.y); p0.y = bfpack(f0.z, f0.w);
        p0.z = bfpack(f1.x, f1.y); p0.w = bfpack(f1.z, f1.w);
        *(uint4*)&As[0][aoff] = p0;
    }
    __syncthreads();

#pragma unroll 2
    for (int kk = 0; kk < 12; ++kk) {
        const int cur = kk & 1;
        LOADB(b1, kk * 2 + 1)              // ks=1 B-frags (hidden by ks0 MFMAs)
        // stage next step (issued after b1 -> b1's wait keeps these in flight)
        float4 f0{}, f1{};
        const bool have = sact && (kk < 11);
        if (have) {
            const int nb = ((kk + 1) >> 2) * 50176 + ((kk + 1) & 3) * 896;
            f0 = *(const float4*)(srow + nb);
            f1 = *(const float4*)(srow + nb + 4);
        }
        short8 afx = *(const short8*)&As[cur][lq * 228 + ard[0]];
        short8 afy = *(const short8*)&As[cur][lq * 228 + ard[1]];
        MFMA12(afx, afy, b0)
        const int kn2 = (kk < 11) ? (kk + 1) * 2 : 0;
        LOADB(bn, kn2)                     // next step ks=0 (hidden by ks1)
        afx = *(const short8*)&As[cur][(4 + lq) * 228 + ard[0]];
        afy = *(const short8*)&As[cur][(4 + lq) * 228 + ard[1]];
        MFMA12(afx, afy, b1)
        // write-late: counted vmcnt for f0/f1 + pack + LDS store
        if (have) {
            uint4 p0;
            p0.x = bfpack(f0.x, f0.y); p0.y = bfpack(f0.z, f0.w);
            p0.z = bfpack(f1.x, f1.y); p0.w = bfpack(f1.z, f1.w);
            *(uint4*)&As[cur ^ 1][aoff] = p0;
        }
#pragma unroll
        for (int ni = 0; ni < 6; ++ni) b0[ni] = bn[ni];
        __syncthreads();
    }
#undef LOADB
#undef MFMA12

    // ---- epilogue: D col = wave*96 + ni*16 + lm; row = lq*4 + r (16 rows)
#pragma unroll
    for (int ni = 0; ni < 6; ++ni) {
        const float bv = bias[wave * 96 + ni * 16 + lm];
#pragma unroll
        for (int r = 0; r < 4; ++r) {
            accx[ni][r] += bv;
            accy[ni][r] += bv;
        }
    }

    // row max over this wave's 96 cols, butterfly within the 16-lane lm group
    float mx[4], my_[4];
#pragma unroll
    for (int r = 0; r < 4; ++r) {
        float a = accx[0][r], bb = accy[0][r];
#pragma unroll
        for (int ni = 1; ni < 6; ++ni) {
            a  = fmaxf(a,  accx[ni][r]);
            bb = fmaxf(bb, accy[ni][r]);
        }
        mx[r] = a; my_[r] = bb;
    }
#pragma unroll
    for (int off = 1; off < 16; off <<= 1)
#pragma unroll
        for (int r = 0; r < 4; ++r) {
            mx[r]  = fmaxf(mx[r],  __shfl_xor(mx[r],  off));
            my_[r] = fmaxf(my_[r], __shfl_xor(my_[r], off));
        }
    if (lm == 0)
#pragma unroll
        for (int r = 0; r < 4; ++r) {
            Smx[wave][lq * 4 + r] = mx[r];
            Smy[wave][lq * 4 + r] = my_[r];
        }
    __syncthreads();
#pragma unroll
    for (int r = 0; r < 4; ++r) {
        const int row = lq * 4 + r;
        mx[r]  = fmaxf(fmaxf(Smx[0][row], Smx[1][row]),
                       fmaxf(Smx[2][row], Smx[3][row]));
        my_[r] = fmaxf(fmaxf(Smy[0][row], Smy[1][row]),
                       fmaxf(Smy[2][row], Smy[3][row]));
    }

    // row sum of exp against the full-row max
    float sx[4], sy[4];
#pragma unroll
    for (int r = 0; r < 4; ++r) {
        float a = 0.f, bb = 0.f;
#pragma unroll
        for (int ni = 0; ni < 6; ++ni) {
            a  += __expf(accx[ni][r] - mx[r]);
            bb += __expf(accy[ni][r] - my_[r]);
        }
        sx[r] = a; sy[r] = bb;
    }
#pragma unroll
    for (int off = 1; off < 16; off <<= 1)
#pragma unroll
        for (int r = 0; r < 4; ++r) {
            sx[r] += __shfl_xor(sx[r], off);
            sy[r] += __shfl_xor(sy[r], off);
        }
    if (lm == 0)
#pragma unroll
        for (int r = 0; r < 4; ++r) {
            Ssx[wave][lq * 4 + r] = sx[r];
            Ssy[wave][lq * 4 + r] = sy[r];
        }
    __syncthreads();
    float shx[4], invy[4];
#pragma unroll
    for (int r = 0; r < 4; ++r) {
        const int row = lq * 4 + r;
        const float ssx = Ssx[0][row] + Ssx[1][row] + Ssx[2][row] + Ssx[3][row];
        const float ssy = Ssy[0][row] + Ssy[1][row] + Ssy[2][row] + Ssy[3][row];
        shx[r]  = mx[r] + __logf(ssx);   // logp shift
        invy[r] = 1.f / ssy;             // q scale
    }

    // ---- T partial (fp32) + packed bf16x2 (logp,q) stores (rows m < 14)
    float T = 0.f;
#pragma unroll
    for (int r = 0; r < 4; ++r) {
        const int m = lq * 4 + r;
        if (m < 14) {
            const size_t lb = ((size_t)(pi * 14 + m) * 64 + img) * 384
                              + wave * 96 + lm;
            const float sh  = shx[r];
            const float mm  = my_[r];
            const float inv = invy[r];
#pragma unroll
            for (int ni = 0; ni < 6; ++ni) {
                const float lp = accx[ni][r] - sh;
                const float qv = __expf(accy[ni][r] - mm) * inv;
                T += lp * qv;
                Zg[lb + ni * 16] = cvtpk(lp, qv);   // bf16 lp | bf16 qv <<16
            }
        }
    }
#pragma unroll
    for (int off = 32; off > 0; off >>= 1) T += __shfl_xor(T, off);
    if (lane == 0) sT[wave] = T;
    __syncthreads();
    if (tid == 0) atomicAdd(&scal[0], sT[0] + sT[1] + sT[2] + sT[3]);
}

// ---------------- fin: per-position L/Q col sums -> S; final scalar ---------
// grid 196 (one block per position; Zg[p] is one contiguous 98 KB stream),
// block 768: (img-half h, col c).
__global__ __launch_bounds__(768) void fin(const unsigned* __restrict__ Zg,
                                           float* __restrict__ scal,
                                           float* __restrict__ out) {
    const int p = blockIdx.x;
    const int t = threadIdx.x;
    const int h = t / 384;                     // img half
    const int c = t - h * 384;                 // 0..383
    float L = 0.f, Q = 0.f;
#pragma unroll 4
    for (int i = 0; i < 32; ++i) {
        const unsigned u = Zg[((size_t)p * 64 + h * 32 + i) * 384 + c];
        L += bf2f(u << 16);
        Q += bf2f(u & 0xffff0000u);
    }
    __shared__ float LL[384], QQ[384];
    if (h == 0) { LL[c] = L; QQ[c] = Q; }
    __syncthreads();
    float s = 0.f;
    if (h == 1) s = (LL[c] + L) * (QQ[c] + Q);
#pragma unroll
    for (int off = 32; off > 0; off >>= 1) s += __shfl_xor(s, off);
    __shared__ float sw[12];
    if ((t & 63) == 0) sw[t >> 6] = s;
    __syncthreads();
    if (t == 0) {
        float Sp = 0.f;
#pragma unroll
        for (int w = 0; w < 12; ++w) Sp += sw[w];
        atomicAdd(&scal[1], Sp);
        __threadfence();
        const int old = atomicAdd((int*)&scal[3], 1);
        if (old == POS - 1) {
            const float T = atomicAdd(&scal[0], 0.f);   // coherent read-back
            const float S = atomicAdd(&scal[1], 0.f);
            out[0] = 63.f * T / (S - T);
        }
    }
}

extern "C" void kernel_launch(void* const* d_in, const int* in_sizes, int n_in,
                              void* d_out, int out_size, void* d_ws, size_t ws_size,
                              hipStream_t stream) {
    const float* x = (const float*)d_in[0];   // (64,3,224,224)
    const float* y = (const float*)d_in[1];   // (64,3,224,224)
    const float* W = (const float*)d_in[2];   // (384,768)
    const float* b = (const float*)d_in[3];   // (384,)
    float* out = (float*)d_out;

    char* ws = (char*)d_ws;
    float*    scal  = (float*)ws;                      // 64 B (pad to 1 KB)
    ushort_t* Wfrag = (ushort_t*)(ws + 1024);          // 589,824 B
    unsigned* Zg    = (unsigned*)(ws + 590848);        // 19,267,584 B

    prep<<<144, 256, 0, stream>>>(W, Wfrag, scal);
    pef<<<896, 256, 0, stream>>>(x, y, Wfrag, b, scal, Zg);
    fin<<<196, 768, 0, stream>>>(Zg, scal, out);
}